// Round 9
// baseline (5661.489 us; speedup 1.0000x reference)
//
#include <hip/hip_runtime.h>
#include <hip/hip_bf16.h>

#define BB 32
#define SS 64
#define TT 63
#define EMBD 512
#define ENCD 1024
#define HIDD 1024
#define VV 32000
#define INTERD 2160
#define LIND 2560
#define TV (TT*VV)
#define OUT_ATT ((long)BB*TT*VV)

typedef float f32;
typedef unsigned short ushort_t;
typedef unsigned long long u64;
typedef __attribute__((ext_vector_type(8))) short bf16x8;
typedef __attribute__((ext_vector_type(4))) float f32x4;
typedef __attribute__((ext_vector_type(8))) unsigned short u16x8;

// ---- ws layout (bytes), total ~82.3 MB ----
#define OFF_LINBF 0L                           /* lin_bf frags 128msub x 80kt = 10,485,760 */
#define OFF_WD    10485760L
#define OFF_WHH0  (OFF_WD + 2097152L)
#define OFF_WIH0C (OFF_WHH0 + 8388608L)
#define OFF_WIH1  (OFF_WIH0C + 8388608L)
#define OFF_WHH1  (OFF_WIH1 + 8388608L)
#define OFF_WEND  (OFF_WHH1 + 8388608L)        /* 46,137,344 */
#define OFF_EG    OFF_WEND                      /* embgate bf16 2048x4096 = 16 MB */
#define OFF_ENCF  OFF_EG                        /* enc frags 4MB, pre-embgate only */
#define OFF_WET   (OFF_EG + 4194304L)           /* We^T frags 2MB, pre-embgate only */
#define OFF_SMCH  OFF_EG                        /* post-loop: sm_W chunk frags <=17.8MB */
#define OFF_EPB   (OFF_EG + 16777216L)          /* enc_proj bf16 4 MB */
#define OFF_EOB   (OFF_EPB + 4194304L)          /* enc_out  bf16 4 MB */
#define OFF_EMBF  (OFF_EOB + 4194304L)          /* emb frags 2 MB */
#define OFF_HWD   (OFF_EMBF + 2097152L)         /* f32 32x1024 (UC, reused addr) */
#define OFF_C0    (OFF_HWD + 131072L)
#define OFF_C1    (OFF_C0 + 131072L)
#define OFF_CNT   (OFF_C1 + 131072L)            /* 4 KB counters */
#define OFF_H0B   (OFF_CNT + 4096L)             /* 64 slots x 64KB (per-step) */
#define OFF_H1B   (OFF_H0B + 4194304L)
#define OFF_CXB   (OFF_H1B + 4194304L)          /* 63 slots x 64KB */
#define OFF_HIDBF OFF_WD                         /* post-loop alias over weights */

__device__ __forceinline__ f32 fast_tanh(f32 x){
    f32 e = __expf(2.0f*x);
    return 1.0f - 2.0f/(e+1.0f);
}
__device__ __forceinline__ f32 fast_sig(f32 x){
    return 1.0f/(1.0f+__expf(-x));
}
__device__ __forceinline__ ushort_t f2bf(f32 x){
    __hip_bfloat16 h = __float2bfloat16(x);
    return *(ushort_t*)&h;
}
__device__ __forceinline__ f32 bf2f(ushort_t u){
    unsigned v = ((unsigned)u) << 16;
    return __uint_as_float(v);
}
// ---- device-scope (LLC write-through) stores for cross-block state ----
__device__ __forceinline__ void uc_st8(u64* p, u64 v){
  __hip_atomic_store(p, v, __ATOMIC_RELAXED, __HIP_MEMORY_SCOPE_AGENT);
}
__device__ __forceinline__ void uc_st4f(f32* p, f32 v){
  __hip_atomic_store(p, v, __ATOMIC_RELAXED, __HIP_MEMORY_SCOPE_AGENT);
}

// fragment element index for (row, k), nkt K-tiles
__device__ __forceinline__ long frag_idx(int row, int k, int nkt){
  return (((long)((row>>4)*nkt + (k>>5)))<<9) + ((row&15) + (((k&31)>>3)<<4))*8 + (k&7);
}

// ================= setup kernels =================
__global__ void k_setup(const f32* __restrict__ c0in, f32* __restrict__ cst,
                        unsigned* __restrict__ cnt){
  int g = blockIdx.x*256 + threadIdx.x;
  if(g < 2*BB*HIDD) cst[g] = c0in[g];
  if(g < 128) cnt[g] = 0;
}

__global__ void k_fill_emb(const f32* __restrict__ emb_table, const int* __restrict__ y,
                           ushort_t* __restrict__ embf, ushort_t* __restrict__ lin_bf){
  int i = blockIdx.x*256 + threadIdx.x;
  if(i >= TT*BB*EMBD) return;
  int e = i & (EMBD-1);
  int tb = i >> 9; int b = tb & 31; int t = tb >> 5;
  int tok = y[b*64 + t];
  ushort_t bv = f2bf(emb_table[(long)tok*EMBD + e]);
  int row = t*32 + b;
  embf[frag_idx(row, e, 16)] = bv;
  lin_bf[frag_idx(row, 2048 + e, 80)] = bv;
}

__global__ void k_cast_eo(const f32* __restrict__ eo, ushort_t* __restrict__ eob){
  int i = blockIdx.x*256 + threadIdx.x;
  if(i < BB*SS*ENCD) eob[i] = f2bf(eo[i]);
}

// ---- fp32 -> bf16 fragment tiles. perm: src row = (r&3)*1024 + (r>>2). tr: transposed src.
__global__ void k_conv(const f32* __restrict__ src, ushort_t* __restrict__ dst,
                       int ld, int rows, int kmax, int nkt, long ntiles, int tr, int perm){
  long g = (long)blockIdx.x*256 + threadIdx.x;
  long tile = g >> 6;
  if(tile >= ntiles) return;
  int lane = (int)(g & 63);
  int kt = (int)(tile % nkt);
  int rsub = (int)(tile / nkt);
  int r = rsub*16 + (lane&15);
  int k0 = kt*32 + ((lane>>4)<<3);
  int rs = perm ? ((r&3)*1024 + (r>>2)) : r;
  u16x8 v;
  if(!tr && r < rows && (k0+8) <= kmax){
    float4 a = *(const float4*)(src + (long)rs*ld + k0);
    float4 b = *(const float4*)(src + (long)rs*ld + k0 + 4);
    v[0]=f2bf(a.x); v[1]=f2bf(a.y); v[2]=f2bf(a.z); v[3]=f2bf(a.w);
    v[4]=f2bf(b.x); v[5]=f2bf(b.y); v[6]=f2bf(b.z); v[7]=f2bf(b.w);
  } else {
    #pragma unroll
    for(int j=0;j<8;j++){
      int k = k0+j;
      f32 x = 0.f;
      if(r < rows && k < kmax) x = tr ? src[(long)k*ld + rs] : src[(long)rs*ld + k];
      v[j] = f2bf(x);
    }
  }
  *(u16x8*)(dst + (tile<<9) + lane*8) = v;
}

// ---- both-frag MFMA: epb = encf @ Wet^T, bf16 out ldc=1024 (grid 16x8)
__global__ __launch_bounds__(256)
void k_mfma_ep(const ushort_t* __restrict__ At, const ushort_t* __restrict__ Bt,
               ushort_t* __restrict__ Cout){
  const int tid = threadIdx.x, wid = tid >> 6, lane = tid & 63;
  const int wm = wid >> 1, wn = wid & 1;
  const int bm = blockIdx.x, bn = blockIdx.y;
  f32x4 acc[4][4] = {};
  for(int kt=0; kt<32; ++kt){
    bf16x8 af[4], bfr[4];
    #pragma unroll
    for(int i=0;i<4;i++){
      af[i]  = *(const bf16x8*)(At + (((long)(bm*8 + wm*4 + i)*32 + kt)<<9) + lane*8);
      bfr[i] = *(const bf16x8*)(Bt + (((long)(bn*8 + wn*4 + i)*32 + kt)<<9) + lane*8);
    }
    #pragma unroll
    for(int mi=0;mi<4;mi++)
      #pragma unroll
      for(int ni=0;ni<4;ni++)
        acc[mi][ni] = __builtin_amdgcn_mfma_f32_16x16x32_bf16(af[mi], bfr[ni], acc[mi][ni], 0, 0, 0);
  }
  #pragma unroll
  for(int mi=0;mi<4;mi++)
    #pragma unroll
    for(int ni=0;ni<4;ni++)
      #pragma unroll
      for(int r=0;r<4;r++){
        int gm = bm*128 + wm*64 + mi*16 + (lane>>4)*4 + r;
        int gn = bn*128 + wn*64 + ni*16 + (lane&15);
        Cout[(long)gm*1024 + gn] = f2bf(acc[mi][ni][r]);
      }
}

// ---- both-frag MFMA logits: out[b][t][n0+gn] = A@B^T + bias
template<int NKT>
__global__ __launch_bounds__(256)
void k_logits(const ushort_t* __restrict__ At, const ushort_t* __restrict__ Bt,
              const f32* __restrict__ bias, f32* __restrict__ out, int n0){
  const int tid = threadIdx.x, wid = tid >> 6, lane = tid & 63;
  const int wm = wid >> 1, wn = wid & 1;
  const int bm = blockIdx.x, bn = blockIdx.y;
  f32x4 acc[4][4] = {};
  for(int kt=0; kt<NKT; ++kt){
    bf16x8 af[4], bfr[4];
    #pragma unroll
    for(int i=0;i<4;i++){
      af[i]  = *(const bf16x8*)(At + (((long)(bm*8 + wm*4 + i)*NKT + kt)<<9) + lane*8);
      bfr[i] = *(const bf16x8*)(Bt + (((long)(bn*8 + wn*4 + i)*NKT + kt)<<9) + lane*8);
    }
    #pragma unroll
    for(int mi=0;mi<4;mi++)
      #pragma unroll
      for(int ni=0;ni<4;ni++)
        acc[mi][ni] = __builtin_amdgcn_mfma_f32_16x16x32_bf16(af[mi], bfr[ni], acc[mi][ni], 0, 0, 0);
  }
  #pragma unroll
  for(int mi=0;mi<4;mi++)
    #pragma unroll
    for(int ni=0;ni<4;ni++)
      #pragma unroll
      for(int r=0;r<4;r++){
        int gm = bm*128 + wm*64 + mi*16 + (lane>>4)*4 + r;
        int gn = bn*128 + wn*64 + ni*16 + (lane&15);
        if(gm < TT*BB){
          int tt = gm >> 5, b = gm & 31;
          out[(long)b*TV + (long)tt*VV + n0 + gn] = acc[mi][ni][r] + bias[gn];
        }
      }
}

// ================= persistent loop kernel =================
// stage 32KB (one msub half) via non-temporal cached loads (fresh per-step addresses)
__device__ __forceinline__ void stage32(ushort_t* Ash, const ushort_t* src, int tid){
  __syncthreads();
  const f32x4* s = (const f32x4*)src;
  f32x4* d = (f32x4*)Ash;
  #pragma unroll
  for(int c=0;c<8;c++) d[c*256 + tid] = __builtin_nontemporal_load(&s[c*256 + tid]);
  __syncthreads();
}

// A(16 rows, LDS) x two B ns-tiles
__device__ __forceinline__ void gemm2(const ushort_t* __restrict__ Ash,
    const ushort_t* __restrict__ B0, const ushort_t* __restrict__ B1, int lane,
    f32x4& a0, f32x4& a1){
  #pragma unroll 4
  for(int kt=0;kt<32;kt++){
    bf16x8 x  = *(const bf16x8*)(Ash + (kt<<9) + lane*8);
    bf16x8 b0 = *(const bf16x8*)(B0 + (kt<<9) + lane*8);
    bf16x8 b1 = *(const bf16x8*)(B1 + (kt<<9) + lane*8);
    a0 = __builtin_amdgcn_mfma_f32_16x16x32_bf16(x, b0, a0, 0, 0, 0);
    a1 = __builtin_amdgcn_mfma_f32_16x16x32_bf16(x, b1, a1, 0, 0, 0);
  }
}
__device__ __forceinline__ void gemm1(const ushort_t* __restrict__ Ash,
    const ushort_t* __restrict__ B0, int lane, f32x4& a0){
  #pragma unroll 4
  for(int kt=0;kt<32;kt++){
    bf16x8 x  = *(const bf16x8*)(Ash + (kt<<9) + lane*8);
    bf16x8 b0 = *(const bf16x8*)(B0 + (kt<<9) + lane*8);
    a0 = __builtin_amdgcn_mfma_f32_16x16x32_bf16(x, b0, a0, 0, 0, 0);
  }
}

// fence-free grid barrier (r5/r7/r8-proven)
__device__ __forceinline__ void gbar(unsigned* __restrict__ cnt, unsigned target,
                                     int tid, int blk){
  asm volatile("s_waitcnt vmcnt(0)" ::: "memory");
  __syncthreads();
  if(tid == 0)
    __hip_atomic_fetch_add(&cnt[(blk & 7)*16], 1u,
                           __ATOMIC_RELAXED, __HIP_MEMORY_SCOPE_AGENT);
  if(tid < 64){
    for(;;){
      unsigned v = (tid < 8) ? __hip_atomic_load(&cnt[tid*16],
                       __ATOMIC_RELAXED, __HIP_MEMORY_SCOPE_AGENT) : 0u;
      v += __shfl_xor(v, 1); v += __shfl_xor(v, 2); v += __shfl_xor(v, 4);
      unsigned tot = __shfl(v, 0);
      if(tot >= target) break;
      __builtin_amdgcn_s_sleep(1);
    }
  }
  __syncthreads();
}

// fused LSTM cell for one ns tile, M=16 rows (bgroup).
// acc rows r -> b = bg*16 + (lane>>4)*4 + r; cols = ns*16+(lane&15) = 4j+q interleaved.
__device__ __forceinline__ void cell_ns(const f32x4& acc, int bg, int ns, int lane,
    f32 bia, const ushort_t* eg_t, f32* __restrict__ cst,
    ushort_t* __restrict__ hdst, ushort_t* __restrict__ ldst){
  const int q = (lane&15)&3;
  const int j = ns*4 + ((lane&15)>>2);
  f32 hv[4];
  #pragma unroll
  for(int r=0;r<4;r++){
    int b = bg*16 + ((lane>>4)<<2) + r;
    f32 v = acc[r] + bia;
    if(eg_t) v += bf2f(__builtin_nontemporal_load(eg_t + (((long)b)<<12) + ns*16 + (lane&15)));
    f32 x1 = __shfl_xor(v,1), x2 = __shfl_xor(v,2), x3 = __shfl_xor(x1,2);
    f32 gi = q==0? v : q==1? x1 : q==2? x2 : x3;
    f32 gf = q==0? x1: q==1? v  : q==2? x3 : x2;
    f32 gg = q==0? x2: q==1? x3 : q==2? v  : x1;
    f32 go = q==0? x3: q==1? x2 : q==2? x1 : v;
    f32 cold = cst[b*HIDD + j];
    f32 cc = fast_sig(gf)*cold + fast_sig(gi)*fast_tanh(gg);
    f32 hh = fast_sig(go)*fast_tanh(cc);
    if(q == 0) cst[b*HIDD + j] = cc;
    hv[r] = hh;
  }
  // pack j..j+3 (lanes Lbase+0/4/8/12, all q==0, jj=0..3) into one u64 per (b,r)
  const int Lbase = lane & 48;
  #pragma unroll
  for(int r=0;r<4;r++){
    f32 h0_ = __shfl(hv[r], Lbase);
    f32 h1_ = __shfl(hv[r], Lbase+4);
    f32 h2_ = __shfl(hv[r], Lbase+8);
    f32 h3_ = __shfl(hv[r], Lbase+12);
    if((lane & 15) == 0){
      u64 pk = (u64)f2bf(h0_) | ((u64)f2bf(h1_)<<16)
             | ((u64)f2bf(h2_)<<32) | ((u64)f2bf(h3_)<<48);
      int b = bg*16 + ((lane>>4)<<2) + r;
      uc_st8((u64*)(hdst + frag_idx(b, ns*4, 32)), pk);
      if(ldst) __builtin_nontemporal_store(pk, (u64*)(ldst + frag_idx(b, ns*4, 80)));
    }
  }
}

__global__ __launch_bounds__(256, 1)
void k_loop(char* __restrict__ ws, const f32* __restrict__ vvec,
            const int* __restrict__ maskp,
            const f32* __restrict__ b_ih0, const f32* __restrict__ b_hh0,
            const f32* __restrict__ b_ih1, const f32* __restrict__ b_hh1,
            f32* __restrict__ out){
  ushort_t* lin_bf = (ushort_t*)(ws + OFF_LINBF);
  const ushort_t* Wdt   = (const ushort_t*)(ws + OFF_WD);
  const ushort_t* Whh0f = (const ushort_t*)(ws + OFF_WHH0);
  const ushort_t* Wih0cf= (const ushort_t*)(ws + OFF_WIH0C);
  const ushort_t* Wih1f = (const ushort_t*)(ws + OFF_WIH1);
  const ushort_t* Whh1f = (const ushort_t*)(ws + OFF_WHH1);
  const ushort_t* eg    = (const ushort_t*)(ws + OFF_EG);
  const ushort_t* epb   = (const ushort_t*)(ws + OFF_EPB);
  const ushort_t* eob   = (const ushort_t*)(ws + OFF_EOB);
  f32* hwd = (f32*)(ws + OFF_HWD);
  f32* c0  = (f32*)(ws + OFF_C0);
  f32* c1  = (f32*)(ws + OFF_C1);
  ushort_t* h0b = (ushort_t*)(ws + OFF_H0B);
  ushort_t* h1b = (ushort_t*)(ws + OFF_H1B);
  ushort_t* cxb = (ushort_t*)(ws + OFF_CXB);
  unsigned* cnt  = (unsigned*)(ws + OFF_CNT);
  f32* attw = out + OUT_ATT;

  const int tid = threadIdx.x, wid = tid >> 6, lane = tid & 63;
  const int blk = blockIdx.x;
  const int bg  = blk >> 5;            // batch group (16 rows)
  const int cg  = blk & 31;            // column group (128 gate-cols = 8 ns tiles)
  const int ns0 = cg*8 + wid*2, ns1 = ns0 + 1;
  const long hoff = (long)bg*16384;    // msub-half offset in 64KB state images

  __shared__ __align__(16) ushort_t Ash[16384];   // 32 KB
  __shared__ f32 hwS[HIDD];
  __shared__ f32 vvS[HIDD];
  __shared__ f32 scs[SS];
  __shared__ f32 wsm[SS];

  for(int i=tid;i<HIDD;i+=256) vvS[i] = vvec[i];

  // per-wave biases for its two ns tiles
  const int q0_ = (lane&15)&3;
  const int j0 = ns0*4 + ((lane&15)>>2), j1 = ns1*4 + ((lane&15)>>2);
  const f32 bia00 = b_ih0[q0_*HIDD + j0] + b_hh0[q0_*HIDD + j0];
  const f32 bia01 = b_ih0[q0_*HIDD + j1] + b_hh0[q0_*HIDD + j1];
  const f32 bia10 = b_ih1[q0_*HIDD + j0] + b_hh1[q0_*HIDD + j0];
  const f32 bia11 = b_ih1[q0_*HIDD + j1] + b_hh1[q0_*HIDD + j1];

  // prologue: g0h(0) = h0_init @ Whh0^T (persist in regs)
  stage32(Ash, h0b + hoff, tid);
  f32x4 g0a = {0.f,0.f,0.f,0.f}, g0b = {0.f,0.f,0.f,0.f};
  gemm2(Ash, Whh0f + ((long)ns0<<14), Whh0f + ((long)ns1<<14), lane, g0a, g0b);

  unsigned bar = 0;
  for(int t=0; t<TT; ++t){
    // ---------- P1: g1h (fresh regs) + hWd (waves 0,1) ----------
    stage32(Ash, h1b + (long)t*32768 + hoff, tid);
    f32x4 g1a = {0.f,0.f,0.f,0.f}, g1b = {0.f,0.f,0.f,0.f};
    gemm2(Ash, Whh1f + ((long)ns0<<14), Whh1f + ((long)ns1<<14), lane, g1a, g1b);
    if(wid < 2){
      int td = cg*2 + wid;
      f32x4 da = {0.f,0.f,0.f,0.f};
      gemm1(Ash, Wdt + ((long)td<<14), lane, da);
      int col = td*16 + (lane&15);
      #pragma unroll
      for(int r=0;r<4;r++){
        int b = bg*16 + ((lane>>4)<<2) + r;
        uc_st4f(&hwd[b*HIDD + col], da[r]);
      }
    }
    bar += 64; gbar(cnt, bar, tid, blk);

    // ---------- P2: attention (blocks 0..31, one per batch row) ----------
    if(blk < 32){
      int b = blk;
      {
        f32x4 hv;
        const f32* hp = hwd + b*HIDD + tid*4;   // reused addr -> stay uncached
        asm volatile("global_load_dwordx4 %0, %1, off sc0 sc1\n\ts_waitcnt vmcnt(0)"
                     : "=v"(hv) : "v"(hp) : "memory");
        *(f32x4*)&hwS[tid*4] = hv;
      }
      __syncthreads();
      #pragma unroll 1
      for(int si=0; si<16; ++si){
        int s = wid*16 + si;
        const ushort_t* ep = epb + ((long)(b*SS+s)<<10) + lane*16;
        u16x8 e0 = *(const u16x8*)ep;
        u16x8 e1 = *(const u16x8*)(ep+8);
        f32 p = 0.f;
        #pragma unroll
        for(int j=0;j<8;j++)
          p = __builtin_fmaf(vvS[lane*16+j], fast_tanh(bf2f(e0[j]) + hwS[lane*16+j]), p);
        #pragma unroll
        for(int j=0;j<8;j++)
          p = __builtin_fmaf(vvS[lane*16+8+j], fast_tanh(bf2f(e1[j]) + hwS[lane*16+8+j]), p);
        #pragma unroll
        for(int off=32; off; off>>=1) p += __shfl_down(p, off);
        if(lane == 0) scs[s] = p;
      }
      __syncthreads();
      if(tid < 64){
        int s = tid;
        f32 x = maskp[b*SS+s] ? scs[s] : -1e9f;
        f32 m = x;
        #pragma unroll
        for(int off=32; off; off>>=1) m = fmaxf(m, __shfl_xor(m, off));
        f32 e = __expf(x - m);
        f32 sum = e;
        #pragma unroll
        for(int off=32; off; off>>=1) sum += __shfl_xor(sum, off);
        f32 w = e/sum;
        wsm[s] = w;
        attw[(long)t*(BB*SS) + b*SS + s] = w;
      }
      __syncthreads();
      if(tid < 128){
        int d0 = tid*8;
        f32 a[8] = {0.f,0.f,0.f,0.f,0.f,0.f,0.f,0.f};
        const ushort_t* eo = eob + ((long)b<<16) + d0;
        #pragma unroll 8
        for(int s=0;s<SS;s++){
          u16x8 v = *(const u16x8*)(eo + ((long)s<<10));
          f32 w = wsm[s];
          #pragma unroll
          for(int j=0;j<8;j++) a[j] = __builtin_fmaf(w, bf2f(v[j]), a[j]);
        }
        u16x8 cf;
        #pragma unroll
        for(int j=0;j<8;j++) cf[j] = f2bf(a[j]);
        u64 lo = (u64)(unsigned short)cf[0] | ((u64)(unsigned short)cf[1]<<16)
               | ((u64)(unsigned short)cf[2]<<32) | ((u64)(unsigned short)cf[3]<<48);
        u64 hi = (u64)(unsigned short)cf[4] | ((u64)(unsigned short)cf[5]<<16)
               | ((u64)(unsigned short)cf[6]<<32) | ((u64)(unsigned short)cf[7]<<48);
        long fi = frag_idx(b, d0, 32);
        ushort_t* cx_t = cxb + (long)t*32768;
        uc_st8((u64*)(cx_t + fi), lo);
        uc_st8((u64*)(cx_t + fi + 4), hi);
        __builtin_nontemporal_store(*(u64*)&lo,
            (u64*)(lin_bf + (long)t*81920 + frag_idx(b, 1024 + d0, 80)));
        __builtin_nontemporal_store(*(u64*)&hi,
            (u64*)(lin_bf + (long)t*81920 + frag_idx(b, 1024 + d0 + 4, 80)));
      }
    }
    bar += 64; gbar(cnt, bar, tid, blk);

    // ---------- P3: g0c accumulate + fused cell0 ----------
    stage32(Ash, cxb + (long)t*32768 + hoff, tid);
    gemm2(Ash, Wih0cf + ((long)ns0<<14), Wih0cf + ((long)ns1<<14), lane, g0a, g0b);
    {
      const ushort_t* eg_t = eg + (((long)(t*BB))<<12);
      ushort_t* h0_t = h0b + (long)(t+1)*32768;
      cell_ns(g0a, bg, ns0, lane, bia00, eg_t, c0, h0_t, (ushort_t*)nullptr);
      cell_ns(g0b, bg, ns1, lane, bia01, eg_t, c0, h0_t, (ushort_t*)nullptr);
    }
    bar += 64; gbar(cnt, bar, tid, blk);

    // ---------- P4: g1x + cell1 + g0h(t+1) ----------
    stage32(Ash, h0b + (long)(t+1)*32768 + hoff, tid);
    gemm2(Ash, Wih1f + ((long)ns0<<14), Wih1f + ((long)ns1<<14), lane, g1a, g1b);
    {
      ushort_t* h1_t = h1b + (long)(t+1)*32768;
      ushort_t* lt = lin_bf + (long)t*81920;
      cell_ns(g1a, bg, ns0, lane, bia10, (const ushort_t*)nullptr, c1, h1_t, lt);
      cell_ns(g1b, bg, ns1, lane, bia11, (const ushort_t*)nullptr, c1, h1_t, lt);
    }
    g0a = (f32x4){0.f,0.f,0.f,0.f}; g0b = (f32x4){0.f,0.f,0.f,0.f};
    gemm2(Ash, Whh0f + ((long)ns0<<14), Whh0f + ((long)ns1<<14), lane, g0a, g0b);
    bar += 64; gbar(cnt, bar, tid, blk);
  }
}

// ================= phase-2 MFMA GEMM, B converted inline from f32 =================
template<int NKT, int EPI, bool PERM>
__global__ __launch_bounds__(256)
void k_mfma2(const ushort_t* __restrict__ At, const f32* __restrict__ B,
             int ldb, int nrowsB, int kmaxB,
             const f32* __restrict__ bias, void* __restrict__ Cout){
  const int tid = threadIdx.x, wid = tid >> 6, lane = tid & 63;
  const int wm = wid >> 1, wn = wid & 1;
  const int bm = blockIdx.x, bn = blockIdx.y;
  f32x4 acc[4][4] = {};
  const int rbase = bn*128 + wn*64 + (lane&15);
  const int kb = (lane>>4)*8;
  for(int kt=0; kt<NKT; ++kt){
    bf16x8 af[4], bfr[4];
    #pragma unroll
    for(int i=0;i<4;i++)
      af[i] = *(const bf16x8*)(At + (((long)(bm*8 + wm*4 + i)*NKT + kt)<<9) + lane*8);
    int k0 = kt*32 + kb;
    #pragma unroll
    for(int i=0;i<4;i++){
      int r = rbase + i*16;
      int rs = PERM ? ((r&3)*1024 + (r>>2)) : r;
      u16x8 v;
      if(r < nrowsB && (k0+8) <= kmaxB){
        float4 x = *(const float4*)(B + (long)rs*ldb + k0);
        float4 y = *(const float4*)(B + (long)rs*ldb + k0 + 4);
        v[0]=f2bf(x.x); v[1]=f2bf(x.y); v[2]=f2bf(x.z); v[3]=f2bf(x.w);
        v[4]=f2bf(y.x); v[5]=f2bf(y.y); v[6]=f2bf(y.z); v[7]=f2bf(y.w);
      } else {
        #pragma unroll
        for(int j=0;j<8;j++){
          int k = k0+j;
          f32 xx = (r < nrowsB && k < kmaxB) ? B[(long)rs*ldb + k] : 0.f;
          v[j] = f2bf(xx);
        }
      }
      bfr[i] = *(bf16x8*)&v;
    }
    #pragma unroll
    for(int mi=0;mi<4;mi++)
      #pragma unroll
      for(int ni=0;ni<4;ni++)
        acc[mi][ni] = __builtin_amdgcn_mfma_f32_16x16x32_bf16(af[mi], bfr[ni], acc[mi][ni], 0, 0, 0);
  }
  #pragma unroll
  for(int mi=0;mi<4;mi++){
    #pragma unroll
    for(int ni=0;ni<4;ni++){
      #pragma unroll
      for(int r=0;r<4;r++){
        int gm = bm*128 + wm*64 + mi*16 + (lane>>4)*4 + r;
        int gn = bn*128 + wn*64 + ni*16 + (lane&15);
        f32 x = acc[mi][ni][r];
        if(EPI == 1){
          x = (gn < INTERD) ? fast_tanh(x + bias[gn]) : 0.f;
          ushort_t* hb = (ushort_t*)Cout;
          int msub = gm >> 4, ktile = gn >> 5;
          int lane_a = (gm & 15) + (((gn & 31) >> 3) << 4);
          hb[(((long)(msub*68 + ktile)) << 9) + lane_a*8 + (gn & 7)] = f2bf(x);
        } else {
          ((ushort_t*)Cout)[((long)gm<<12) + gn] = f2bf(x);
        }
      }
    }
  }
}

extern "C" void kernel_launch(void* const* d_in, const int* in_sizes, int n_in,
                              void* d_out, int out_size, void* d_ws, size_t ws_size,
                              hipStream_t stream){
  (void)in_sizes; (void)n_in; (void)out_size; (void)ws_size;
  const f32* enc_output = (const f32*)d_in[0];
  const int* mask  = (const int*)d_in[1];
  const int* y     = (const int*)d_in[2];
  const f32* dec_h0= (const f32*)d_in[3];
  const f32* dec_c0= (const f32*)d_in[4];
  const f32* emb   = (const f32*)d_in[5];
  const f32* We    = (const f32*)d_in[6];
  const f32* Wd    = (const f32*)d_in[7];
  const f32* vvec  = (const f32*)d_in[8];
  const f32* W_ih0 = (const f32*)d_in[9];
  const f32* W_hh0 = (const f32*)d_in[10];
  const f32* b_ih0 = (const f32*)d_in[11];
  const f32* b_hh0 = (const f32*)d_in[12];
  const f32* W_ih1 = (const f32*)d_in[13];
  const f32* W_hh1 = (const f32*)d_in[14];
  const f32* b_ih1 = (const f32*)d_in[15];
  const f32* b_hh1 = (const f32*)d_in[16];
  const f32* out_W = (const f32*)d_in[17];
  const f32* out_b = (const f32*)d_in[18];
  const f32* sm_W  = (const f32*)d_in[19];
  const f32* sm_b  = (const f32*)d_in[20];
  f32* out = (f32*)d_out;
  char* ws = (char*)d_ws;

  ushort_t* lin_bf = (ushort_t*)(ws + OFF_LINBF);
  ushort_t* epb = (ushort_t*)(ws + OFF_EPB);
  ushort_t* eob = (ushort_t*)(ws + OFF_EOB);
  ushort_t* encf  = (ushort_t*)(ws + OFF_ENCF);
  ushort_t* wetf  = (ushort_t*)(ws + OFF_WET);
  ushort_t* embf  = (ushort_t*)(ws + OFF_EMBF);
  ushort_t* egbuf = (ushort_t*)(ws + OFF_EG);
  ushort_t* smch  = (ushort_t*)(ws + OFF_SMCH);
  ushort_t* hid_bf = (ushort_t*)(ws + OFF_HIDBF);

  // ---- setup ----
  k_setup<<<dim3(256), dim3(256), 0, stream>>>(dec_c0, (f32*)(ws + OFF_C0),
                                               (unsigned*)(ws + OFF_CNT));
  k_fill_emb<<<dim3(4032), dim3(256), 0, stream>>>(emb, y, embf, lin_bf);
  k_conv<<<dim3(1024), dim3(256), 0, stream>>>(enc_output, encf, ENCD, BB*SS, ENCD, 32, 128L*32, 0, 0);
  k_conv<<<dim3(512),  dim3(256), 0, stream>>>(We,         wetf, HIDD, HIDD,  ENCD, 32, 64L*32, 1, 0);
  k_mfma_ep<<<dim3(16,8), dim3(256), 0, stream>>>(encf, wetf, epb);
  k_cast_eo<<<dim3(8192), dim3(256), 0, stream>>>(enc_output, eob);

  // embgate = emb @ Wih0e_perm^T -> bf16 [2048][4096] (overwrites encf/wetf)
  k_mfma2<16,3,true><<<dim3(16,32), dim3(256), 0, stream>>>(
      embf, W_ih0, 1536, 4096, 512, (const f32*)nullptr, egbuf);

  // ---- weight frags (gate-interleaved perm) ----
  k_conv<<<dim3(512),  dim3(256), 0, stream>>>(Wd,        (ushort_t*)(ws+OFF_WD),    HIDD, HIDD, HIDD, 32, 64L*32, 1, 0);
  k_conv<<<dim3(2048), dim3(256), 0, stream>>>(W_hh0,     (ushort_t*)(ws+OFF_WHH0),  HIDD, 4096, HIDD, 32, 256L*32, 0, 1);
  k_conv<<<dim3(2048), dim3(256), 0, stream>>>(W_ih0+512, (ushort_t*)(ws+OFF_WIH0C), 1536, 4096, HIDD, 32, 256L*32, 0, 1);
  k_conv<<<dim3(2048), dim3(256), 0, stream>>>(W_ih1,     (ushort_t*)(ws+OFF_WIH1),  HIDD, 4096, HIDD, 32, 256L*32, 0, 1);
  k_conv<<<dim3(2048), dim3(256), 0, stream>>>(W_hh1,     (ushort_t*)(ws+OFF_WHH1),  HIDD, 4096, HIDD, 32, 256L*32, 0, 1);
  // initial h frags -> slot 0
  k_conv<<<dim3(16),   dim3(256), 0, stream>>>(dec_h0,       (ushort_t*)(ws+OFF_H0B), HIDD, BB, HIDD, 32, 64, 0, 0);
  k_conv<<<dim3(16),   dim3(256), 0, stream>>>(dec_h0+32768, (ushort_t*)(ws+OFF_H1B), HIDD, BB, HIDD, 32, 64, 0, 0);

  // ---- the 63-step recurrence: 64 blocks, (bgroup, colgroup) decomposition ----
  k_loop<<<dim3(64), dim3(256), 0, stream>>>(ws, vvec, mask,
      b_ih0, b_hh0, b_ih1, b_hh1, out);

  // ---- phase 2 ----
  k_mfma2<80,1,false><<<dim3(16,17), dim3(256), 0, stream>>>(
      lin_bf, out_W, LIND, INTERD, LIND, out_b, hid_bf);
  for(int c=0; c<8; ++c){
    int n0 = c*4096;
    int rows = (c<7) ? 4096 : 3328;
    int nsub = rows >> 4;
    long ntiles = (long)nsub*68;
    k_conv<<<dim3((unsigned)((ntiles*64+255)/256)), dim3(256), 0, stream>>>(
        sm_W + (long)n0*INTERD, smch, INTERD, rows, INTERD, 68, ntiles, 0, 0);
    k_logits<68><<<dim3(16, nsub/8), dim3(256), 0, stream>>>(
        hid_bf, smch, sm_b + n0, out, n0);
  }
}